// Round 3
// baseline (2817.818 us; speedup 1.0000x reference)
//
#include <hip/hip_runtime.h>
#include <hip/hip_bf16.h>
#include <math.h>

#define NOUTK 1024
#define PHK   512
#define HID   24
#define G4    96
#define LSTEPS 32
#define BATCH 8192
#define EPB   16

// Static LDS: 65,472 B (<= 64 KiB, no dynamic-LDS opt-in needed).
struct Smem {
  float  stg[HID][64][8];    // active w_lin half, f32: [k][chunk][col] 49152 B
  float  whhT[HID][G4];      // w_hh transposed [k][row]                 9216 B
  float  bihs[G4], bhhs[G4]; //                                           768 B
  double hsh[EPB][25];       // h state (f64)                            3200 B
  double scr[8][EPB];        // red (max/sum) + candr alias              1024 B
  double tots[8][EPB];       // per-slice prob totals                    1024 B
  double Msh[EPB], invSm[EPB], ush[EPB], r0sh[EPB];                  //   512 B
  int    candj[8][EPB];      //                                           512 B
  int    actsh[EPB];         // previous action (-1 = zeros one-hot)       64 B
};

__device__ __forceinline__ float bf2f(unsigned short v) {
  union { unsigned u; float f; } x; x.u = ((unsigned)v) << 16; return x.f;
}
__device__ __forceinline__ unsigned short f2bf(float f) {
  unsigned u = __float_as_uint(f);
  unsigned r = 0x7FFFu + ((u >> 16) & 1u);
  return (unsigned short)((u + r) >> 16);
}
__device__ __forceinline__ float bfsnap(float f) {  // snap to bf16 grid
  return bf2f(f2bf(f));
}
__device__ __forceinline__ float ldf(const void* p, int idx, int mode) {
  return mode ? ((const float*)p)[idx] : bf2f(((const unsigned short*)p)[idx]);
}

// Input-dtype sniff: u ~ Uniform[0,1). bf16 buffer => every aligned ushort is
// a bf16 in [0,1) => < 0x3F80 < 0x8000 always. f32 buffer => even-index
// ushorts are random mantissa halves => >= 0x8000 within 64 samples w.p.
// 1 - 2^-64.   0 = bf16 inputs, 1 = f32 inputs.
__global__ void sniff_kernel(const unsigned short* __restrict__ u, int* __restrict__ flag) {
  if (threadIdx.x == 0 && blockIdx.x == 0) {
    int m = 0;
    for (int i = 0; i < 64; ++i) if (u[2 * i] >= 0x8000u) m = 1;
    *flag = m;
  }
}

__global__ __launch_bounds__(1024, 4)
void policy_kernel(const void* __restrict__ wih_,  const void* __restrict__ whh_,
                   const void* __restrict__ bih_,  const void* __restrict__ bhh_,
                   const void* __restrict__ wlin_, const void* __restrict__ blin_,
                   const void* __restrict__ u_,    void* __restrict__ outg_,
                   const int* __restrict__ flagp) {
  __shared__ Smem sm;
  const int mode = *flagp;                  // grid-uniform
  const int tid  = threadIdx.x;
  const int wave = tid >> 6;                // 16 waves; wave w owns element w
  const int lane = tid & 63;
  const int s    = wave & 7;                // slice: 64 active cols
  const int eg   = (wave >> 3) << 3;        // element group base (0 or 8)
  const int le   = lane & 7;                // element within group
  const int jl   = lane >> 3;               // 8-col chunk within slice
  const int eG   = eg + le;                 // element this thread computes for
  const int geL  = blockIdx.x * EPB + wave; // owner's global batch element
  const int jgl0 = s * 64 + jl * 8;         // active-local col of r=0

  // ---------------- one-time staging ----------------
  for (int i = tid; i < G4 * HID; i += 1024) {
    const int row = i / HID, k = i % HID;   // coalesced global read
    sm.whhT[k][row] = ldf(whh_, i, mode);
  }
  if (tid < G4) { sm.bihs[tid] = ldf(bih_, tid, mode);
                  sm.bhhs[tid] = ldf(bhh_, tid, mode); }
  if (tid < EPB * 25) ((double*)sm.hsh)[tid] = 0.0;
  if (tid < EPB) sm.actsh[tid] = -1;
  __syncthreads();

  double creg = 0.0;                        // c state: lanes<24 of owner wave

  for (int t = 0; t < LSTEPS; ++t) {
    const int odd  = t & 1;
    const int base = odd ? PHK : 0;

    // ---------------- stage active w_lin half (all 1024 threads) ---------
    if (mode) {
      const float4* wl4 = (const float4*)wlin_ + base * 6;   // base*24 floats
      #pragma unroll
      for (int ii = 0; ii < 3; ++ii) {
        const int i = tid + ii * 1024;                       // i = cl*6 + k4
        const float4 v = wl4[i];
        const int cl = i / 6, k4 = (i % 6) * 4;
        const int c = cl >> 3, r = cl & 7;
        sm.stg[k4 + 0][c][r] = v.x; sm.stg[k4 + 1][c][r] = v.y;
        sm.stg[k4 + 2][c][r] = v.z; sm.stg[k4 + 3][c][r] = v.w;
      }
    } else {
      const ushort4* wl4 = (const ushort4*)wlin_ + base * 6; // base*24 bf16s
      #pragma unroll
      for (int ii = 0; ii < 3; ++ii) {
        const int i = tid + ii * 1024;
        const ushort4 v = wl4[i];
        const int cl = i / 6, k4 = (i % 6) * 4;
        const int c = cl >> 3, r = cl & 7;
        sm.stg[k4 + 0][c][r] = bf2f(v.x); sm.stg[k4 + 1][c][r] = bf2f(v.y);
        sm.stg[k4 + 2][c][r] = bf2f(v.z); sm.stg[k4 + 3][c][r] = bf2f(v.w);
      }
    }

    // ---------------- phase L: LSTM cell (owner wave, lanes 0..23) -------
    if (lane < HID) {
      const int a = sm.actsh[wave];
      double hk[HID];
      #pragma unroll
      for (int k = 0; k < HID; ++k) hk[k] = sm.hsh[wave][k];
      double g[4];
      #pragma unroll
      for (int q = 0; q < 4; ++q) {
        const int row = q * HID + lane;
        const double colA = (a >= 0) ? (double)ldf(wih_, row * NOUTK + a, mode) : 0.0;
        double mv = 0.0;
        #pragma unroll
        for (int k = 0; k < HID; ++k)
          mv = fma(hk[k], (double)sm.whhT[k][row], mv);
        g[q] = ((colA + (double)sm.bihs[row]) + mv) + (double)sm.bhhs[row];
      }
      const double ig = 1.0 / (1.0 + exp(-g[0]));
      const double fg = 1.0 / (1.0 + exp(-g[1]));
      const double gv = tanh(g[2]);
      const double og = 1.0 / (1.0 + exp(-g[3]));
      creg = fg * creg + ig * gv;
      sm.hsh[wave][lane] = og * tanh(creg);
    }
    if (lane == 32)
      sm.ush[wave] = (double)ldf(u_, t * BATCH + geL, mode);
    __syncthreads();                                  // b1

    // ---------------- phase G: active-half logits (8 cols/thread, f64) ---
    double z[8];
    #pragma unroll
    for (int r = 0; r < 8; ++r) z[r] = 0.0;
    {
      const int c = s * 8 + jl;
      #pragma unroll
      for (int k = 0; k < HID; ++k) {
        const double hk = sm.hsh[eG][k];
        const float4 wa = *(const float4*)&sm.stg[k][c][0];
        const float4 wb = *(const float4*)&sm.stg[k][c][4];
        z[0] = fma(hk, (double)wa.x, z[0]); z[1] = fma(hk, (double)wa.y, z[1]);
        z[2] = fma(hk, (double)wa.z, z[2]); z[3] = fma(hk, (double)wa.w, z[3]);
        z[4] = fma(hk, (double)wb.x, z[4]); z[5] = fma(hk, (double)wb.y, z[5]);
        z[6] = fma(hk, (double)wb.z, z[6]); z[7] = fma(hk, (double)wb.w, z[7]);
      }
    }
    if (mode) {
      const float4* bl4 = (const float4*)blin_ + (base + jgl0) / 4;
      const float4 b0 = bl4[0], b1 = bl4[1];
      z[0] += (double)b0.x; z[1] += (double)b0.y; z[2] += (double)b0.z; z[3] += (double)b0.w;
      z[4] += (double)b1.x; z[5] += (double)b1.y; z[6] += (double)b1.z; z[7] += (double)b1.w;
    } else {
      const uint4 bu = *((const uint4*)blin_ + (base + jgl0) / 8);
      z[0] += (double)__uint_as_float(bu.x << 16); z[1] += (double)__uint_as_float(bu.x & 0xFFFF0000u);
      z[2] += (double)__uint_as_float(bu.y << 16); z[3] += (double)__uint_as_float(bu.y & 0xFFFF0000u);
      z[4] += (double)__uint_as_float(bu.z << 16); z[5] += (double)__uint_as_float(bu.z & 0xFFFF0000u);
      z[6] += (double)__uint_as_float(bu.w << 16); z[7] += (double)__uint_as_float(bu.w & 0xFFFF0000u);
    }

    // ---------------- softmax max over active half ----
    // (e_i/Sm is invariant to max shift and full-softmax denominator to
    //  ~1e-16 relative — safe at f64 decision margins)
    double pm = z[0];
    #pragma unroll
    for (int r = 1; r < 8; ++r) pm = fmax(pm, z[r]);
    pm = fmax(pm, __shfl_xor(pm, 8));
    pm = fmax(pm, __shfl_xor(pm, 16));
    pm = fmax(pm, __shfl_xor(pm, 32));
    if (jl == 0) sm.scr[s][eG] = pm;
    __syncthreads();                                  // b2
    if (lane < 8) {
      double v = sm.scr[lane][wave];
      v = fmax(v, __shfl_xor(v, 1));
      v = fmax(v, __shfl_xor(v, 2));
      v = fmax(v, __shfl_xor(v, 4));
      if (lane == 0) sm.Msh[wave] = v;
    }
    __syncthreads();                                  // b3

    // ---------------- exp + masked-sum Sm -> inv ----
    const double Me = sm.Msh[eG];
    double ex[8], ps = 0.0;
    #pragma unroll
    for (int r = 0; r < 8; ++r) { ex[r] = exp(z[r] - Me); ps += ex[r]; }
    ps += __shfl_xor(ps, 8);
    ps += __shfl_xor(ps, 16);
    ps += __shfl_xor(ps, 32);
    if (jl == 0) sm.scr[s][eG] = ps;
    __syncthreads();                                  // b4
    if (lane < 8) {
      double v = sm.scr[lane][wave];
      v += __shfl_xor(v, 1);
      v += __shfl_xor(v, 2);
      v += __shfl_xor(v, 4);
      if (lane == 0) sm.invSm[wave] = 1.0 / v;
    }
    __syncthreads();                                  // b5

    // ---------------- rr = e/Sm, blocked prefix ----
    const double inv = sm.invSm[eG];
    double rr[8], pref[8];
    #pragma unroll
    for (int r = 0; r < 8; ++r) rr[r] = ex[r] * inv;
    pref[0] = rr[0];
    #pragma unroll
    for (int r = 1; r < 8; ++r) pref[r] = pref[r - 1] + rr[r];
    const double tch = pref[7];
    double exbase = 0.0, acc = 0.0;
    #pragma unroll
    for (int q2 = 0; q2 < 8; ++q2) {
      const double tq = __shfl(tch, q2 * 8 + le);
      if (q2 == jl) exbase = acc;
      acc += tq;
    }
    if (jl == 0) sm.tots[s][eG] = acc;
    if (s == 0 && lane < 8) sm.r0sh[eG] = rr[0];
    __syncthreads();                                  // b6

    // ---------------- crossing search ----
    double sb = exbase;
    for (int i = 0; i < s; ++i) sb += sm.tots[i][eG];
    const double ue = sm.ush[eG];
    int jloc = 0x7FFFFFFF; double rsel = 0.0;
    #pragma unroll
    for (int r = 0; r < 8; ++r) {
      const double C = sb + pref[r];
      if (jloc == 0x7FFFFFFF && C > ue) { jloc = jgl0 + r; rsel = rr[r]; }
    }
    { int oj = __shfl_xor(jloc, 8);  double orr = __shfl_xor(rsel, 8);  if (oj < jloc) { jloc = oj; rsel = orr; } }
    { int oj = __shfl_xor(jloc, 16); double orr = __shfl_xor(rsel, 16); if (oj < jloc) { jloc = oj; rsel = orr; } }
    { int oj = __shfl_xor(jloc, 32); double orr = __shfl_xor(rsel, 32); if (oj < jloc) { jloc = oj; rsel = orr; } }
    if (jl == 0) { sm.candj[s][eG] = jloc; sm.scr[s][eG] = rsel; }
    __syncthreads();                                  // b7

    // ---------------- owner: combine slices, emit ----
    if (lane < 8) {
      int cj = sm.candj[lane][wave]; double cr = sm.scr[lane][wave];
      { int oj = __shfl_xor(cj, 1); double orr = __shfl_xor(cr, 1); if (oj < cj) { cj = oj; cr = orr; } }
      { int oj = __shfl_xor(cj, 2); double orr = __shfl_xor(cr, 2); if (oj < cj) { cj = oj; cr = orr; } }
      { int oj = __shfl_xor(cj, 4); double orr = __shfl_xor(cr, 4); if (oj < cj) { cj = oj; cr = orr; } }
      if (lane == 0) {
        int actg; double p;
        if (cj == 0x7FFFFFFF) {               // cumsum never exceeded u:
          actg = 0;                           // np.argmax(all False) == 0
          p = odd ? 0.0 : sm.r0sh[wave];      // out[0] (masked -> 0 on odd)
        } else {
          actg = base + cj; p = cr;
        }
        sm.actsh[wave] = actg;
        const int io = geL * LSTEPS + t;
        if (mode) {
          ((float*)outg_)[io]                  = bfsnap((float)p);
          ((float*)outg_)[BATCH * LSTEPS + io] = bfsnap((float)actg);
        } else {
          ((unsigned short*)outg_)[io]                  = f2bf((float)p);
          ((unsigned short*)outg_)[BATCH * LSTEPS + io] = f2bf((float)actg);
        }
      }
    }
    __syncthreads();                                  // b8
  }
}

extern "C" void kernel_launch(void* const* d_in, const int* in_sizes, int n_in,
                              void* d_out, int out_size, void* d_ws, size_t ws_size,
                              hipStream_t stream) {
  (void)in_sizes; (void)n_in; (void)out_size; (void)ws_size;
  int* flag = (int*)d_ws;
  sniff_kernel<<<1, 64, 0, stream>>>((const unsigned short*)d_in[6], flag);
  policy_kernel<<<BATCH / EPB, 1024, 0, stream>>>(
      d_in[0], d_in[1], d_in[2], d_in[3], d_in[4], d_in[5], d_in[6],
      d_out, flag);
}

// Round 4
// 2245.136 us; speedup vs baseline: 1.2551x; 1.2551x over previous
//
#include <hip/hip_runtime.h>
#include <hip/hip_bf16.h>
#include <math.h>

#define NOUTK 1024
#define PHK   512
#define HID   24
#define G4    96
#define LSTEPS 32
#define BATCH 8192
#define EPB   16

// Static LDS: 65,472 B (fits the 64 KiB static limit; LDS_Block_Size 65536).
struct Smem {
  float  stg[HID][64][8];    // active w_lin half f32: [k][chunk][col]  49152 B
  float  whhT[HID][G4];      // w_hh transposed [k][row]                 9216 B
  float  bihs[G4], bhhs[G4]; //                                           768 B
  double hsh[EPB][25];       // h state f64 (pad 25 -> conflict-free)    3200 B
  double scr[8][EPB];        // max/sum partials + candr alias           1024 B
  double tots[8][EPB];       // per-slice prob totals                    1024 B
  double Msh[EPB], invSm[EPB], ush[EPB], r0sh[EPB];                  //   512 B
  int    candj[8][EPB];      //                                           512 B
  int    actsh[EPB];         // previous action (-1 = zeros one-hot)       64 B
};

__device__ __forceinline__ float bf2f(unsigned short v) {
  union { unsigned u; float f; } x; x.u = ((unsigned)v) << 16; return x.f;
}
__device__ __forceinline__ unsigned short f2bf(float f) {
  unsigned u = __float_as_uint(f);
  unsigned r = 0x7FFFu + ((u >> 16) & 1u);
  return (unsigned short)((u + r) >> 16);
}
__device__ __forceinline__ float bfsnap(float f) { return bf2f(f2bf(f)); }

// waves_per_eu(4,4): tell the allocator exactly 4 waves/SIMD (128-VGPR
// budget). R3's (1024,4) launch_bounds let the compiler squeeze to 64 VGPRs
// (it saw 64KB LDS -> 2 blocks/CU) and spill the f64 working set: 5.5 GB of
// scratch WRITE_SIZE per launch. 1 block/CU with zero spills is the win.
__attribute__((amdgpu_waves_per_eu(4, 4)))
__global__ void __launch_bounds__(1024)
policy_kernel(const float* __restrict__ wihf,  const float* __restrict__ whhf,
              const float* __restrict__ bihf,  const float* __restrict__ bhhf,
              const float* __restrict__ wlinf, const float* __restrict__ blinf,
              const float* __restrict__ uf,    float* __restrict__ outg) {
  __shared__ Smem sm;
  const int tid  = threadIdx.x;
  const int wave = tid >> 6;                // 16 waves; wave w owns element w
  const int lane = tid & 63;
  const int s    = wave & 7;                // slice: 64 active cols
  const int eg   = (wave >> 3) << 3;        // element group base (0 or 8)
  const int le   = lane & 7;                // element within group
  const int jl   = lane >> 3;               // 8-col chunk within slice
  const int eG   = eg + le;                 // element this thread computes for
  const int geL  = blockIdx.x * EPB + wave; // owner's global batch element
  const int jgl0 = s * 64 + jl * 8;         // active-local col of r=0
  const int c    = s * 8 + jl;              // stg chunk (parity-independent)

  // ---------------- one-time staging ----------------
  for (int i = tid; i < G4 * HID; i += 1024) {
    const int row = i / HID, k = i % HID;   // coalesced global read
    sm.whhT[k][row] = whhf[i];
  }
  if (tid < G4) { sm.bihs[tid] = bihf[tid]; sm.bhhs[tid] = bhhf[tid]; }
  if (tid < EPB * 25) ((double*)sm.hsh)[tid] = 0.0;
  if (tid < EPB) sm.actsh[tid] = -1;

  const float4* wl4 = (const float4*)wlinf;   // w_lin row j = 6 float4s
  const float4* bl4 = (const float4*)blinf;
  float4 pf[3];                               // staged half for step t
  #pragma unroll
  for (int ii = 0; ii < 3; ++ii) pf[ii] = wl4[tid + ii * 1024];  // t=0: even

  double creg = 0.0;                        // c state: lanes<24 of owner wave
  __syncthreads();

  for (int t = 0; t < LSTEPS; ++t) {
    const int odd  = t & 1;
    const int base = odd ? PHK : 0;

    // ---- stash prefetched half to LDS, then prefetch step t+1's half ----
    #pragma unroll
    for (int ii = 0; ii < 3; ++ii) {
      const int i  = tid + ii * 1024;       // float4 index within half
      const int cl = i / 6, k4 = (i % 6) * 4;
      const int cc = cl >> 3, r = cl & 7;
      const float4 v = pf[ii];
      sm.stg[k4 + 0][cc][r] = v.x; sm.stg[k4 + 1][cc][r] = v.y;
      sm.stg[k4 + 2][cc][r] = v.z; sm.stg[k4 + 3][cc][r] = v.w;
    }
    {
      const int nb = ((t + 1) & 1) * 3072;  // next half, float4 units
      #pragma unroll
      for (int ii = 0; ii < 3; ++ii) pf[ii] = wl4[nb + tid + ii * 1024];
    }
    // bias for this step (consumed after GEMM ~3000 cy later)
    const float4 bza = bl4[(base + jgl0) >> 2];
    const float4 bzb = bl4[((base + jgl0) >> 2) + 1];
    if (lane == 32) sm.ush[wave] = (double)uf[t * BATCH + geL];

    // ---------------- phase L: LSTM cell (owner wave, lanes 0..23) -------
    if (lane < HID) {
      const int a = sm.actsh[wave];
      double hk[HID];
      #pragma unroll
      for (int k = 0; k < HID; ++k) hk[k] = sm.hsh[wave][k];
      double g[4];
      #pragma unroll
      for (int q = 0; q < 4; ++q) {
        const int row = q * HID + lane;
        const double colA = (a >= 0) ? (double)wihf[row * NOUTK + a] : 0.0;
        double mv = 0.0;
        #pragma unroll
        for (int k = 0; k < HID; ++k)
          mv = fma(hk[k], (double)sm.whhT[k][row], mv);
        g[q] = ((colA + (double)sm.bihs[row]) + mv) + (double)sm.bhhs[row];
      }
      const double ig = 1.0 / (1.0 + exp(-g[0]));
      const double fg = 1.0 / (1.0 + exp(-g[1]));
      const double gv = tanh(g[2]);
      const double og = 1.0 / (1.0 + exp(-g[3]));
      creg = fg * creg + ig * gv;
      sm.hsh[wave][lane] = og * tanh(creg);
    }
    __syncthreads();                                  // b1

    // ---------------- phase G: active-half logits (8 cols/thread, f64) ---
    double z[8];
    #pragma unroll
    for (int r = 0; r < 8; ++r) z[r] = 0.0;
    #pragma unroll
    for (int k = 0; k < HID; ++k) {
      const double hk = sm.hsh[eG][k];
      const float4 wa = *(const float4*)&sm.stg[k][c][0];
      const float4 wb = *(const float4*)&sm.stg[k][c][4];
      z[0] = fma(hk, (double)wa.x, z[0]); z[1] = fma(hk, (double)wa.y, z[1]);
      z[2] = fma(hk, (double)wa.z, z[2]); z[3] = fma(hk, (double)wa.w, z[3]);
      z[4] = fma(hk, (double)wb.x, z[4]); z[5] = fma(hk, (double)wb.y, z[5]);
      z[6] = fma(hk, (double)wb.z, z[6]); z[7] = fma(hk, (double)wb.w, z[7]);
    }
    z[0] += (double)bza.x; z[1] += (double)bza.y; z[2] += (double)bza.z; z[3] += (double)bza.w;
    z[4] += (double)bzb.x; z[5] += (double)bzb.y; z[6] += (double)bzb.z; z[7] += (double)bzb.w;

    // ---------------- softmax max over active half ----
    // (e_i/Sm is invariant to max shift and the full-softmax denominator to
    //  ~1e-16 relative — safe at f64 decision margins)
    double pm = z[0];
    #pragma unroll
    for (int r = 1; r < 8; ++r) pm = fmax(pm, z[r]);
    pm = fmax(pm, __shfl_xor(pm, 8));
    pm = fmax(pm, __shfl_xor(pm, 16));
    pm = fmax(pm, __shfl_xor(pm, 32));
    if (jl == 0) sm.scr[s][eG] = pm;
    __syncthreads();                                  // b2
    if (lane < 8) {
      double v = sm.scr[lane][wave];
      v = fmax(v, __shfl_xor(v, 1));
      v = fmax(v, __shfl_xor(v, 2));
      v = fmax(v, __shfl_xor(v, 4));
      if (lane == 0) sm.Msh[wave] = v;
    }
    __syncthreads();                                  // b3

    // ---------------- exp (in place) + masked-sum Sm -> inv ----
    const double Me = sm.Msh[eG];
    double ps = 0.0;
    #pragma unroll
    for (int r = 0; r < 8; ++r) { z[r] = exp(z[r] - Me); ps += z[r]; }
    ps += __shfl_xor(ps, 8);
    ps += __shfl_xor(ps, 16);
    ps += __shfl_xor(ps, 32);
    if (jl == 0) sm.scr[s][eG] = ps;
    __syncthreads();                                  // b4
    if (lane < 8) {
      double v = sm.scr[lane][wave];
      v += __shfl_xor(v, 1);
      v += __shfl_xor(v, 2);
      v += __shfl_xor(v, 4);
      if (lane == 0) sm.invSm[wave] = 1.0 / v;
    }
    __syncthreads();                                  // b5

    // ---------------- rr = e/Sm (in place), blocked prefix ----
    const double inv = sm.invSm[eG];
    double pref[8];
    #pragma unroll
    for (int r = 0; r < 8; ++r) z[r] = z[r] * inv;
    pref[0] = z[0];
    #pragma unroll
    for (int r = 1; r < 8; ++r) pref[r] = pref[r - 1] + z[r];
    const double tch = pref[7];
    double exbase = 0.0, acc = 0.0;
    #pragma unroll
    for (int q2 = 0; q2 < 8; ++q2) {
      const double tq = __shfl(tch, q2 * 8 + le);
      if (q2 == jl) exbase = acc;
      acc += tq;
    }
    if (jl == 0) sm.tots[s][eG] = acc;
    if (s == 0 && lane < 8) sm.r0sh[eG] = z[0];
    __syncthreads();                                  // b6

    // ---------------- crossing search ----
    double sb = exbase;
    for (int i = 0; i < s; ++i) sb += sm.tots[i][eG];
    const double ue = sm.ush[eG];
    int jloc = 0x7FFFFFFF; double rsel = 0.0;
    #pragma unroll
    for (int r = 0; r < 8; ++r) {
      const double C = sb + pref[r];
      if (jloc == 0x7FFFFFFF && C > ue) { jloc = jgl0 + r; rsel = z[r]; }
    }
    { int oj = __shfl_xor(jloc, 8);  double orr = __shfl_xor(rsel, 8);  if (oj < jloc) { jloc = oj; rsel = orr; } }
    { int oj = __shfl_xor(jloc, 16); double orr = __shfl_xor(rsel, 16); if (oj < jloc) { jloc = oj; rsel = orr; } }
    { int oj = __shfl_xor(jloc, 32); double orr = __shfl_xor(rsel, 32); if (oj < jloc) { jloc = oj; rsel = orr; } }
    if (jl == 0) { sm.candj[s][eG] = jloc; sm.scr[s][eG] = rsel; }
    __syncthreads();                                  // b7

    // ---------------- owner: combine slices, emit ----
    // (no trailing barrier: b1(t+1) already fences every LDS reuse)
    if (lane < 8) {
      int cj = sm.candj[lane][wave]; double cr = sm.scr[lane][wave];
      { int oj = __shfl_xor(cj, 1); double orr = __shfl_xor(cr, 1); if (oj < cj) { cj = oj; cr = orr; } }
      { int oj = __shfl_xor(cj, 2); double orr = __shfl_xor(cr, 2); if (oj < cj) { cj = oj; cr = orr; } }
      { int oj = __shfl_xor(cj, 4); double orr = __shfl_xor(cr, 4); if (oj < cj) { cj = oj; cr = orr; } }
      if (lane == 0) {
        int actg; double p;
        if (cj == 0x7FFFFFFF) {               // cumsum never exceeded u:
          actg = 0;                           // np.argmax(all False) == 0
          p = odd ? 0.0 : sm.r0sh[wave];      // out[0] (masked -> 0 on odd)
        } else {
          actg = base + cj; p = cr;
        }
        sm.actsh[wave] = actg;
        const int io = geL * LSTEPS + t;
        outg[io]                  = bfsnap((float)p);
        outg[BATCH * LSTEPS + io] = bfsnap((float)actg);
      }
    }
  }
}

extern "C" void kernel_launch(void* const* d_in, const int* in_sizes, int n_in,
                              void* d_out, int out_size, void* d_ws, size_t ws_size,
                              hipStream_t stream) {
  (void)in_sizes; (void)n_in; (void)out_size; (void)d_ws; (void)ws_size;
  policy_kernel<<<BATCH / EPB, 1024, 0, stream>>>(
      (const float*)d_in[0], (const float*)d_in[1], (const float*)d_in[2],
      (const float*)d_in[3], (const float*)d_in[4], (const float*)d_in[5],
      (const float*)d_in[6], (float*)d_out);
}